// Round 3
// baseline (3820.664 us; speedup 1.0000x reference)
//
#include <hip/hip_runtime.h>
#include <hip/hip_bf16.h>
#include <stdint.h>

#define L 1024
#define D 1024
#define NLAYER 4
#define NSTATE 16
#define DI 2048
#define DTR 64
#define KCONV 4
#define XD 96      // DTR + 2*NSTATE
#define NC 64      // scan chunks
#define CT 16      // timesteps per chunk (L/NC)
#define KSPLIT 16  // x_proj split-K (256 tiles)
#define OSPLIT 4   // out_proj split-K (512 tiles)
#define BK 32
#define DIST 4     // GEMM prefetch depth (iterations)
#define GRID 512
#define NTHR 256
#define SMEM_BYTES (2 * 128 * BK * 2 + 2 * 64 * BK * 2)  // 24576

typedef __attribute__((ext_vector_type(8))) short short8;
typedef __attribute__((ext_vector_type(4))) float floatx4;

__device__ __forceinline__ float siluf(float x) { return x / (1.f + __expf(-x)); }

__device__ __forceinline__ unsigned short f2bf(float x) {
    __hip_bfloat16 b = __float2bfloat16(x);
    return *reinterpret_cast<unsigned short*>(&b);
}

__device__ __forceinline__ short8 pack8(floatx4 a, floatx4 b) {
    short8 o;
    o[0] = (short)f2bf(a.x); o[1] = (short)f2bf(a.y);
    o[2] = (short)f2bf(a.z); o[3] = (short)f2bf(a.w);
    o[4] = (short)f2bf(b.x); o[5] = (short)f2bf(b.y);
    o[6] = (short)f2bf(b.z); o[7] = (short)f2bf(b.w);
    return o;
}

// Block-level barrier that does NOT drain vmcnt (deep global prefetch stays in flight).
#define BARRIER_NODRAIN() asm volatile("s_waitcnt lgkmcnt(0)\n\ts_barrier" ::: "memory")

// ---------------- grid-wide barrier (sense-reversal, device scope) ----------------
// bar[0]=arrival counter, bar[1]=generation. __threadfence() = agent-scope fence:
// wbL2/invL2 on gfx950, required for cross-XCD visibility (G16). Works under both
// cooperative and plain launch (residency guaranteed by launch_bounds(256,2)+24KB LDS
// -> 2 blocks/CU x 256 CUs = 512 = grid).
__device__ __forceinline__ void gridbar(unsigned int* bar) {
    __syncthreads();   // all waves' stores drained to L2
    if (threadIdx.x == 0) {
        __threadfence();  // release: prior writes device-visible
        unsigned int gen = __hip_atomic_load(&bar[1], __ATOMIC_RELAXED, __HIP_MEMORY_SCOPE_AGENT);
        unsigned int old = __hip_atomic_fetch_add(&bar[0], 1u, __ATOMIC_RELAXED, __HIP_MEMORY_SCOPE_AGENT);
        if (old == GRID - 1) {
            __hip_atomic_store(&bar[0], 0u, __ATOMIC_RELAXED, __HIP_MEMORY_SCOPE_AGENT);
            __hip_atomic_fetch_add(&bar[1], 1u, __ATOMIC_RELEASE, __HIP_MEMORY_SCOPE_AGENT);
        } else {
            while (__hip_atomic_load(&bar[1], __ATOMIC_RELAXED, __HIP_MEMORY_SCOPE_AGENT) == gen)
                __builtin_amdgcn_s_sleep(2);
        }
        __threadfence();  // acquire: see other blocks' writes
    }
    __syncthreads();
}

// ---------------- XCD chunk map: block bid (round-robin over 8 XCDs) -> linear id ----------------
__device__ __forceinline__ int xmap(int bid, int T) {
    return (bid & 7) * (T >> 3) + (bid >> 3);
}

// ---------------- pipelined MFMA GEMM stage: C[M,N] = A[M,K] * B[N,K]^T ----------------
// 128x64 tile, 4 waves 2x2, register prefetch queue of DIST iterations.
// EPI: 0 plain; 1 softplus(c + bias[n]).
template <int EPI, int ITERS>
__device__ __forceinline__ void gemm_stage(
    uint8_t* smemraw,
    const __hip_bfloat16* __restrict__ A, int lda,
    const float* __restrict__ Bw, int ldb, int Brows,
    float* __restrict__ C, int ldc, int Nvalid,
    const float* __restrict__ bias,
    int bm, int bn, int k_base) {
    typedef __hip_bfloat16 (*AsT)[128 * BK];
    typedef __hip_bfloat16 (*BsT)[64 * BK];
    AsT As = (AsT)smemraw;
    BsT Bs = (BsT)(smemraw + 2 * 128 * BK * 2);
    int tid = threadIdx.x;
    int wave = tid >> 6, lane = tid & 63;
    int m0 = bm * 128, n0 = bn * 64;
    int wr = wave >> 1, wc = wave & 1;
    int srow = lane >> 2, scol = (lane & 3) * 8;
    int q = lane >> 4, r = lane & 15;

    floatx4 acc[4][2] = {};

    const __hip_bfloat16* gA0 = A + (long)(m0 + wave * 32 + srow) * lda + scol + k_base;
    const __hip_bfloat16* gA1 = gA0 + (long)16 * lda;
    int bnrow = n0 + wave * 16 + srow;
    const float* gB = Bw + (long)bnrow * ldb + scol + k_base;
    bool bok = bnrow < Brows;

    short8 qa0[DIST], qa1[DIST];
    floatx4 qb0[DIST] = {}, qb1[DIST] = {};

    auto ld = [&](int j) {
        int k0 = j * BK;
        int s = j & (DIST - 1);
        qa0[s] = *(const short8*)(gA0 + k0);
        qa1[s] = *(const short8*)(gA1 + k0);
        if (bok) {
            qb0[s] = *(const floatx4*)(gB + k0);
            qb1[s] = *(const floatx4*)(gB + k0 + 4);
        }
    };
    auto wrstage = [&](int j) {
        int p = j & 1, s = j & (DIST - 1);
        *(short8*)(&As[p][(wave * 32 + srow) * BK + scol]) = qa0[s];
        *(short8*)(&As[p][(wave * 32 + 16 + srow) * BK + scol]) = qa1[s];
        *(short8*)(&Bs[p][(wave * 16 + srow) * BK + scol]) = pack8(qb0[s], qb1[s]);
    };

#pragma unroll
    for (int j = 0; j < DIST; ++j)
        if (j < ITERS) ld(j);
    wrstage(0);

#pragma unroll
    for (int k = 0; k < ITERS; ++k) {
        BARRIER_NODRAIN();
        if (k + DIST < ITERS) ld(k + DIST);
        if (k + 1 < ITERS) wrstage(k + 1);
        const short* Ap = (const short*)As[k & 1];
        const short* Bp = (const short*)Bs[k & 1];
        short8 af[4], bfr[2];
#pragma unroll
        for (int i = 0; i < 4; ++i)
            af[i] = *(const short8*)(Ap + (wr * 64 + i * 16 + r) * BK + q * 8);
#pragma unroll
        for (int j = 0; j < 2; ++j)
            bfr[j] = *(const short8*)(Bp + (wc * 32 + j * 16 + r) * BK + q * 8);
#pragma unroll
        for (int i = 0; i < 4; ++i)
#pragma unroll
            for (int j = 0; j < 2; ++j)
                acc[i][j] = __builtin_amdgcn_mfma_f32_16x16x32_bf16(af[i], bfr[j], acc[i][j], 0, 0, 0);
    }

#pragma unroll
    for (int i = 0; i < 4; ++i) {
        int mrow = m0 + wr * 64 + i * 16 + q * 4;
#pragma unroll
        for (int j = 0; j < 2; ++j) {
            int ncol = n0 + wc * 32 + j * 16 + r;
            if (ncol < Nvalid) {
#pragma unroll
                for (int rr = 0; rr < 4; ++rr) {
                    float v = acc[i][j][rr];
                    int m = mrow + rr;
                    if (EPI == 1) {
                        v += bias[ncol];
                        v = v > 20.f ? v : log1pf(__expf(v));
                    }
                    C[(long)m * ldc + ncol] = v;
                }
            }
        }
    }
    // block-level sync before smem reuse happens inside next gridbar
}

struct MegaParams {
    const float *x, *norm_w, *in_w, *conv_w, *conv_b, *xproj_w, *dt_w, *dt_b, *A_log, *D_skip, *out_w;
    float* out;
    __hip_bfloat16 *xn, *u, *xdbl, *yg;
    float *xz, *part, *xdblBC, *delta, *part2, *Ach, *Bch;
    unsigned int* bar;
};

// ================= the whole network in one dispatch =================
__global__ __launch_bounds__(NTHR, 2) void mega_kernel(MegaParams p) {
    const int bid = blockIdx.x;
    const int tid = threadIdx.x;
    __shared__ __align__(16) uint8_t smem[SMEM_BYTES];

    // ---- pre: RMSNorm layer 0 (2 rows per block) ----
    {
        float* red = (float*)smem;
        const float* __restrict__ xg = p.x;
        for (int rr = 0; rr < 2; ++rr) {
            int row = bid * 2 + rr;
            const float* xr = xg + (size_t)row * D;
            float v[4];
            float s = 0.f;
#pragma unroll
            for (int i = 0; i < 4; ++i) {
                v[i] = xr[tid + i * 256];
                s += v[i] * v[i];
            }
#pragma unroll
            for (int off = 32; off > 0; off >>= 1) s += __shfl_xor(s, off, 64);
            if ((tid & 63) == 0) red[tid >> 6] = s;
            __syncthreads();
            float inv = rsqrtf((red[0] + red[1] + red[2] + red[3]) * (1.f / D) + 1e-5f);
#pragma unroll
            for (int i = 0; i < 4; ++i) {
                int c = tid + i * 256;
                p.xn[(size_t)row * D + c] = __float2bfloat16(v[i] * inv * p.norm_w[c]);
            }
            __syncthreads();
        }
    }
    gridbar(p.bar);

    for (int l = 0; l < NLAYER; ++l) {
        // ---- S1: in_proj [1024,1024]x[4096,1024]^T -> xz (512 tiles of 128x64) ----
        {
            int lid = xmap(bid, 512);
            int bn = lid >> 3, bm = lid & 7;
            gemm_stage<0, 32>(smem, p.xn, D, p.in_w + (size_t)l * 4096 * 1024, D, 4096,
                              p.xz, 4096, 4096, nullptr, bm, bn, 0);
        }
        gridbar(p.bar);

        // ---- S2: causal depthwise conv + SiLU -> u (bf16) ----
        {
            const float* __restrict__ xz = p.xz;
            const float* __restrict__ cw = p.conv_w + (size_t)l * DI * KCONV;
            const float* __restrict__ cb = p.conv_b + (size_t)l * DI;
#pragma unroll
            for (int it = 0; it < (L * DI) / (GRID * NTHR); ++it) {
                int idx = it * (GRID * NTHR) + bid * NTHR + tid;
                int d = idx & (DI - 1);
                int t = idx >> 11;
                float acc = cb[d];
#pragma unroll
                for (int k = 0; k < KCONV; ++k) {
                    int tk = t - (KCONV - 1) + k;
                    if (tk >= 0) acc += xz[(size_t)tk * (2 * DI) + d] * cw[d * KCONV + k];
                }
                p.u[idx] = __float2bfloat16(siluf(acc));
            }
        }
        gridbar(p.bar);

        // ---- S3: x_proj split-K=16 -> part[16][1024][96] (256 tiles) ----
        if (bid < 256) {
            int lid = xmap(bid, 256);
            int bm = lid & 7, bn = (lid >> 3) & 1, bz = lid >> 4;
            gemm_stage<0, 2048 / (KSPLIT * BK)>(
                smem, p.u, DI, p.xproj_w + (size_t)l * 96 * 2048, DI, 96,
                p.part + (size_t)bz * L * XD, XD, XD, nullptr, bm, bn, bz * (2048 / KSPLIT));
        }
        gridbar(p.bar);

        // ---- S4: xred -> xdbl (bf16) + xdblBC (f32) ----
        {
            int i = bid * NTHR + tid;
            if (i < L * XD) {
                int t = i / XD, col = i - t * XD;
                float s = 0.f;
#pragma unroll
                for (int sp = 0; sp < KSPLIT; ++sp) s += p.part[(size_t)sp * L * XD + i];
                if (col < DTR) p.xdbl[(size_t)t * DTR + col] = __float2bfloat16(s);
                else p.xdblBC[(size_t)t * 32 + (col - DTR)] = s;
            }
        }
        gridbar(p.bar);

        // ---- S5: dt_proj [1024,64]x[2048,64]^T -> delta (softplus+bias), 256 tiles ----
        if (bid < 256) {
            int lid = xmap(bid, 256);
            int bn = lid >> 3, bm = lid & 7;
            gemm_stage<1, 2>(smem, p.xdbl, DTR, p.dt_w + (size_t)l * 2048 * 64, DTR, 2048,
                             p.delta, DI, DI, p.dt_b + (size_t)l * DI, bm, bn, 0);
        }
        gridbar(p.bar);

        // ---- S6: scanA (per-chunk aggregates), 512 blocks = 8 dgrp x 64 chunks ----
        {
            int d = (bid & 7) * NTHR + tid;
            int c = bid >> 3;
            float* Bsh = (float*)smem;
            Bsh[tid] = p.xdblBC[(size_t)(c * CT + (tid >> 4)) * 32 + (tid & 15)];
            __syncthreads();

            float aval[NSTATE];
            const float4* Al4 = (const float4*)(p.A_log + (size_t)l * DI * NSTATE + (size_t)d * NSTATE);
#pragma unroll
            for (int n4 = 0; n4 < 4; ++n4) {
                float4 t = Al4[n4];
                aval[n4 * 4 + 0] = -__expf(t.x);
                aval[n4 * 4 + 1] = -__expf(t.y);
                aval[n4 * 4 + 2] = -__expf(t.z);
                aval[n4 * 4 + 3] = -__expf(t.w);
            }
            float h[NSTATE], ap[NSTATE];
#pragma unroll
            for (int n = 0; n < NSTATE; ++n) { h[n] = 0.f; ap[n] = 1.f; }

            const float* __restrict__ delta = p.delta;
            const __hip_bfloat16* __restrict__ u = p.u;
            for (int tt = 0; tt < CT; ++tt) {
                int t = c * CT + tt;
                float dl = delta[(size_t)t * DI + d];
                float uu = __bfloat162float(u[(size_t)t * DI + d]);
                float du = dl * uu;
                const float4* Bv = (const float4*)(Bsh + tt * NSTATE);
#pragma unroll
                for (int n4 = 0; n4 < 4; ++n4) {
                    float4 b = Bv[n4];
                    float bb[4] = {b.x, b.y, b.z, b.w};
#pragma unroll
                    for (int k = 0; k < 4; ++k) {
                        int n = n4 * 4 + k;
                        float a = __expf(dl * aval[n]);
                        h[n] = a * h[n] + du * bb[k];
                        ap[n] *= a;
                    }
                }
            }
            float4* Ao = (float4*)(p.Ach + ((size_t)c * DI + d) * NSTATE);
            float4* Bo = (float4*)(p.Bch + ((size_t)c * DI + d) * NSTATE);
#pragma unroll
            for (int n4 = 0; n4 < 4; ++n4) {
                Ao[n4] = make_float4(ap[n4 * 4], ap[n4 * 4 + 1], ap[n4 * 4 + 2], ap[n4 * 4 + 3]);
                Bo[n4] = make_float4(h[n4 * 4], h[n4 * 4 + 1], h[n4 * 4 + 2], h[n4 * 4 + 3]);
            }
        }
        gridbar(p.bar);

        // ---- S7: scanB (chunk combine, pipelined), 128 blocks ----
        if (bid < (DI * NSTATE) / NTHR) {
            long i = (long)bid * NTHR + tid;
            const long S = (long)DI * NSTATE;
            constexpr int P = 8;
            float ab[P], bb[P];
#pragma unroll
            for (int j = 0; j < P; ++j) {
                ab[j] = p.Ach[(long)j * S + i];
                bb[j] = p.Bch[(long)j * S + i];
            }
            float h = 0.f;
#pragma unroll
            for (int c = 0; c < NC; ++c) {
                float a = ab[c & (P - 1)];
                float b = bb[c & (P - 1)];
                p.Ach[(long)c * S + i] = h;  // becomes Hinit
                if (c + P < NC) {
                    ab[c & (P - 1)] = p.Ach[(long)(c + P) * S + i];
                    bb[c & (P - 1)] = p.Bch[(long)(c + P) * S + i];
                }
                h = a * h + b;
            }
        }
        gridbar(p.bar);

        // ---- S8: scanC (replay + gate) -> yg (bf16) ----
        {
            int d = (bid & 7) * NTHR + tid;
            int c = bid >> 3;
            float* Bsh = (float*)smem;
            float* Csh = Bsh + CT * NSTATE;
            Bsh[tid] = p.xdblBC[(size_t)(c * CT + (tid >> 4)) * 32 + (tid & 15)];
            Csh[tid] = p.xdblBC[(size_t)(c * CT + (tid >> 4)) * 32 + 16 + (tid & 15)];
            __syncthreads();

            float aval[NSTATE];
            const float4* Al4 = (const float4*)(p.A_log + (size_t)l * DI * NSTATE + (size_t)d * NSTATE);
#pragma unroll
            for (int n4 = 0; n4 < 4; ++n4) {
                float4 t = Al4[n4];
                aval[n4 * 4 + 0] = -__expf(t.x);
                aval[n4 * 4 + 1] = -__expf(t.y);
                aval[n4 * 4 + 2] = -__expf(t.z);
                aval[n4 * 4 + 3] = -__expf(t.w);
            }
            float h[NSTATE];
            const float4* Hi = (const float4*)(p.Ach + ((size_t)c * DI + d) * NSTATE);
#pragma unroll
            for (int n4 = 0; n4 < 4; ++n4) {
                float4 t = Hi[n4];
                h[n4 * 4 + 0] = t.x; h[n4 * 4 + 1] = t.y; h[n4 * 4 + 2] = t.z; h[n4 * 4 + 3] = t.w;
            }
            float dsk = p.D_skip[(size_t)l * DI + d];

            const float* __restrict__ delta = p.delta;
            const __hip_bfloat16* __restrict__ u = p.u;
            const float* __restrict__ xz = p.xz;
            for (int tt = 0; tt < CT; ++tt) {
                int t = c * CT + tt;
                float dl = delta[(size_t)t * DI + d];
                float uu = __bfloat162float(u[(size_t)t * DI + d]);
                float du = dl * uu;
                const float4* Bv = (const float4*)(Bsh + tt * NSTATE);
                const float4* Cv = (const float4*)(Csh + tt * NSTATE);
                float y = 0.f;
#pragma unroll
                for (int n4 = 0; n4 < 4; ++n4) {
                    float4 b = Bv[n4];
                    float4 cc = Cv[n4];
                    float bb[4] = {b.x, b.y, b.z, b.w};
                    float cv[4] = {cc.x, cc.y, cc.z, cc.w};
#pragma unroll
                    for (int k = 0; k < 4; ++k) {
                        int n = n4 * 4 + k;
                        float a = __expf(dl * aval[n]);
                        h[n] = a * h[n] + du * bb[k];
                        y += h[n] * cv[k];
                    }
                }
                float z = xz[(size_t)t * (2 * DI) + DI + d];
                p.yg[(size_t)t * DI + d] = __float2bfloat16((y + uu * dsk) * siluf(z));
            }
        }
        gridbar(p.bar);

        // ---- S9: out_proj split-K=4 [1024,2048]x[1024,2048]^T -> part2 (512 tiles) ----
        {
            int lid = xmap(bid, 512);
            int bm = lid & 7, bn = (lid >> 3) & 15, bz = lid >> 7;
            gemm_stage<0, 2048 / (OSPLIT * BK)>(
                smem, p.yg, DI, p.out_w + (size_t)l * 1024 * 2048, DI, 1024,
                p.part2 + (size_t)bz * L * D, D, D, nullptr, bm, bn, bz * (2048 / OSPLIT));
        }
        gridbar(p.bar);

        // ---- S10: reduce + residual (+RMSNorm for next layer), 2 rows per block ----
        {
            const float* xin = (l == 0) ? p.x : p.out;
            bool donorm = (l < NLAYER - 1);
            float* red = (float*)smem;
            for (int rr = 0; rr < 2; ++rr) {
                int row = bid * 2 + rr;
                const float* xr = xin + (size_t)row * D;
                float v[4];
                float ss = 0.f;
#pragma unroll
                for (int i = 0; i < 4; ++i) {
                    int c = tid + i * 256;
                    float s = xr[c];
#pragma unroll
                    for (int pp = 0; pp < OSPLIT; ++pp)
                        s += p.part2[(size_t)pp * L * D + (size_t)row * D + c];
                    v[i] = s;
                    p.out[(size_t)row * D + c] = s;
                    ss += s * s;
                }
                if (donorm) {
#pragma unroll
                    for (int off = 32; off > 0; off >>= 1) ss += __shfl_xor(ss, off, 64);
                    if ((tid & 63) == 0) red[tid >> 6] = ss;
                    __syncthreads();
                    float inv = rsqrtf((red[0] + red[1] + red[2] + red[3]) * (1.f / D) + 1e-5f);
#pragma unroll
                    for (int i = 0; i < 4; ++i) {
                        int c = tid + i * 256;
                        p.xn[(size_t)row * D + c] =
                            __float2bfloat16(v[i] * inv * p.norm_w[(size_t)(l + 1) * D + c]);
                    }
                }
                __syncthreads();
            }
        }
        gridbar(p.bar);
    }
}

// ---------------- host orchestration ----------------
extern "C" void kernel_launch(void* const* d_in, const int* in_sizes, int n_in,
                              void* d_out, int out_size, void* d_ws, size_t ws_size,
                              hipStream_t stream) {
    uint8_t* wp = (uint8_t*)d_ws;
    auto alloc = [&](size_t bytes) {
        uint8_t* p = wp;
        wp += (bytes + 255) & ~(size_t)255;
        return p;
    };
    MegaParams prm;
    prm.x      = (const float*)d_in[0];
    prm.norm_w = (const float*)d_in[1];
    prm.in_w   = (const float*)d_in[2];
    prm.conv_w = (const float*)d_in[3];
    prm.conv_b = (const float*)d_in[4];
    prm.xproj_w= (const float*)d_in[5];
    prm.dt_w   = (const float*)d_in[6];
    prm.dt_b   = (const float*)d_in[7];
    prm.A_log  = (const float*)d_in[8];
    prm.D_skip = (const float*)d_in[9];
    prm.out_w  = (const float*)d_in[10];
    prm.out    = (float*)d_out;

    prm.xn     = (__hip_bfloat16*)alloc((size_t)L * D * 2);
    prm.xz     = (float*)alloc((size_t)L * 2 * DI * 4);
    prm.u      = (__hip_bfloat16*)alloc((size_t)L * DI * 2);
    prm.part   = (float*)alloc((size_t)KSPLIT * L * XD * 4);
    prm.xdbl   = (__hip_bfloat16*)alloc((size_t)L * DTR * 2);
    prm.xdblBC = (float*)alloc((size_t)L * 32 * 4);
    prm.delta  = (float*)alloc((size_t)L * DI * 4);
    prm.yg     = (__hip_bfloat16*)alloc((size_t)L * DI * 2);
    prm.part2  = (float*)alloc((size_t)OSPLIT * L * D * 4);
    prm.Ach    = (float*)alloc((size_t)NC * DI * NSTATE * 4);  // Hinit aliases this
    prm.Bch    = (float*)alloc((size_t)NC * DI * NSTATE * 4);
    prm.bar    = (unsigned int*)alloc(256);

    // barrier counters must start at 0 (workspace is poisoned by the harness)
    hipMemsetAsync((void*)prm.bar, 0, 256, stream);

    void* args[] = { &prm };
    hipError_t e = hipLaunchCooperativeKernel((const void*)mega_kernel,
                                              dim3(GRID), dim3(NTHR), args, 0u, stream);
    if (e != hipSuccess) {
        // fallback: plain launch — residency still guaranteed by occupancy
        // (launch_bounds(256,2) -> VGPR<=256, 24KB LDS -> 2 blocks/CU x 256 CUs = 512)
        hipLaunchKernelGGL(mega_kernel, dim3(GRID), dim3(NTHR), 0, stream, prm);
    }
}

// Round 4
// 1369.131 us; speedup vs baseline: 2.7906x; 2.7906x over previous
//
#include <hip/hip_runtime.h>
#include <hip/hip_bf16.h>
#include <stdint.h>

#define L 1024
#define D 1024
#define NLAYER 4
#define NSTATE 16
#define DI 2048
#define DTR 64
#define KCONV 4
#define XD 96      // DTR + 2*NSTATE
#define NC 64      // scan chunks
#define CT 16      // timesteps per chunk
#define KSPLIT 16  // x_proj split-K
#define OSPLIT 4   // out_proj split-K
#define BK 32
#define GRID 512
#define NTHR 256
#define SMEM_BYTES 24576

typedef __attribute__((ext_vector_type(8))) short short8;
typedef __attribute__((ext_vector_type(4))) float floatx4;

__device__ __forceinline__ float siluf(float x) { return x / (1.f + __expf(-x)); }

__device__ __forceinline__ unsigned short f2bf(float x) {
    __hip_bfloat16 b = __float2bfloat16(x);
    return *reinterpret_cast<unsigned short*>(&b);
}

__device__ __forceinline__ short8 pack8(floatx4 a, floatx4 b) {
    short8 o;
    o[0] = (short)f2bf(a.x); o[1] = (short)f2bf(a.y);
    o[2] = (short)f2bf(a.z); o[3] = (short)f2bf(a.w);
    o[4] = (short)f2bf(b.x); o[5] = (short)f2bf(b.y);
    o[6] = (short)f2bf(b.z); o[7] = (short)f2bf(b.w);
    return o;
}

// ---------- device-scope (sc1) accessors: write-through to LLC / bypass stale L2 ----------
__device__ __forceinline__ void st_dev_u32(uint32_t* p, uint32_t v) {
    __hip_atomic_store(p, v, __ATOMIC_RELAXED, __HIP_MEMORY_SCOPE_AGENT);
}
__device__ __forceinline__ void st_dev_f(float* p, float v) {
    union { float f; uint32_t u; } c; c.f = v;
    __hip_atomic_store((uint32_t*)p, c.u, __ATOMIC_RELAXED, __HIP_MEMORY_SCOPE_AGENT);
}
__device__ __forceinline__ void st_dev_u64(void* p, uint64_t v) {
    __hip_atomic_store((unsigned long long*)p, (unsigned long long)v, __ATOMIC_RELAXED, __HIP_MEMORY_SCOPE_AGENT);
}
__device__ __forceinline__ float ld_dev_f(const float* p) {
    uint32_t u = __hip_atomic_load((uint32_t*)p, __ATOMIC_RELAXED, __HIP_MEMORY_SCOPE_AGENT);
    union { uint32_t u; float f; } c; c.u = u;
    return c.f;
}

// Block-level LDS-only barrier for the GEMM pipeline (vm prefetches stay in flight).
#define BARRIER_NODRAIN() asm volatile("s_waitcnt lgkmcnt(0)\n\ts_barrier" ::: "memory")

// ---------------- flush-free grid barrier ----------------
// No threadfence/cacheops: all cross-stage data is stored with sc1 (write-through),
// so there are no dirty L2 lines to write back. Ordering: vmcnt(0) before arrival
// guarantees this block's sc1 stores reached the LLC. Two-level monotonic counters
// (8 leaf counters x 64 blocks -> 1 top counter -> generation broadcast).
__device__ __forceinline__ void gridbar(uint32_t* bar, uint32_t tgt) {
    __syncthreads();
    if (threadIdx.x == 0) {
        asm volatile("s_waitcnt vmcnt(0)" ::: "memory");
        uint32_t* leaf = bar + (blockIdx.x >> 6) * 32;   // 64 blocks per leaf
        uint32_t* top  = bar + 8 * 32;
        uint32_t* gen  = bar + 9 * 32;
        uint32_t old = __hip_atomic_fetch_add(leaf, 1u, __ATOMIC_RELAXED, __HIP_MEMORY_SCOPE_AGENT);
        if (old == tgt * 64u - 1u) {
            uint32_t o2 = __hip_atomic_fetch_add(top, 1u, __ATOMIC_RELAXED, __HIP_MEMORY_SCOPE_AGENT);
            if (o2 == tgt * 8u - 1u)
                __hip_atomic_store(gen, tgt, __ATOMIC_RELAXED, __HIP_MEMORY_SCOPE_AGENT);
        }
        while (__hip_atomic_load(gen, __ATOMIC_RELAXED, __HIP_MEMORY_SCOPE_AGENT) < tgt)
            __builtin_amdgcn_s_sleep(4);
        asm volatile("" ::: "memory");
    }
    __syncthreads();
}

// ---------------- XCD chunk map (perf-only heuristic) ----------------
__device__ __forceinline__ int xmap(int bid, int T) {
    return (bid & 7) * (T >> 3) + (bid >> 3);
}

// ---------------- pipelined MFMA GEMM stage: C[M,N] = A[M,K] * B[N,K]^T ----------------
// 128x64 tile, 4 waves 2x2, register prefetch queue of QD iterations.
// A: bf16 (AF32=false) or f32 converted in staging (AF32=true). B always f32->bf16.
// A/B loads: NORMAL cached (A buffers rotate per layer -> never stale).
// C stores: sc1 scalar. EPI: 0 plain; 1 softplus(c + bias[n]).
template <int EPI, int ITERS, bool AF32, int QD>
__device__ __forceinline__ void gemm_stage(
    uint8_t* smemraw, const void* Aptr, int lda,
    const float* __restrict__ Bw, int ldb, int Brows,
    float* __restrict__ C, int ldc, int Nvalid,
    const float* __restrict__ bias,
    int bm, int bn, int k_base) {
    __hip_bfloat16* As = (__hip_bfloat16*)smemraw;                       // [2][128*BK]
    __hip_bfloat16* Bs = (__hip_bfloat16*)(smemraw + 2 * 128 * BK * 2);  // [2][64*BK]
    int tid = threadIdx.x;
    int wave = tid >> 6, lane = tid & 63;
    int m0 = bm * 128, n0 = bn * 64;
    int wr = wave >> 1, wc = wave & 1;
    int srow = lane >> 2, scol = (lane & 3) * 8;
    int q = lane >> 4, r = lane & 15;

    floatx4 acc[4][2] = {};

    int arow0 = m0 + wave * 32 + srow;
    const __hip_bfloat16* gA0 = nullptr; const __hip_bfloat16* gA1 = nullptr;
    const float* gAf0 = nullptr; const float* gAf1 = nullptr;
    if (AF32) {
        gAf0 = (const float*)Aptr + (long)arow0 * lda + scol + k_base;
        gAf1 = gAf0 + (long)16 * lda;
    } else {
        gA0 = (const __hip_bfloat16*)Aptr + (long)arow0 * lda + scol + k_base;
        gA1 = gA0 + (long)16 * lda;
    }
    int bnrow = n0 + wave * 16 + srow;
    const float* gB = Bw + (long)bnrow * ldb + scol + k_base;
    bool bok = bnrow < Brows;

    short8 qa0[QD], qa1[QD];
    floatx4 qaf[QD][4];
    floatx4 qb0[QD] = {}, qb1[QD] = {};

    auto ld = [&](int j) {
        int k0 = j * BK;
        int s = j & (QD - 1);
        if (AF32) {
            qaf[s][0] = *(const floatx4*)(gAf0 + k0);
            qaf[s][1] = *(const floatx4*)(gAf0 + k0 + 4);
            qaf[s][2] = *(const floatx4*)(gAf1 + k0);
            qaf[s][3] = *(const floatx4*)(gAf1 + k0 + 4);
        } else {
            qa0[s] = *(const short8*)(gA0 + k0);
            qa1[s] = *(const short8*)(gA1 + k0);
        }
        if (bok) {
            qb0[s] = *(const floatx4*)(gB + k0);
            qb1[s] = *(const floatx4*)(gB + k0 + 4);
        }
    };
    auto wrstage = [&](int j) {
        int p = j & 1, s = j & (QD - 1);
        if (AF32) {
            *(short8*)(&As[p * 128 * BK + (wave * 32 + srow) * BK + scol]) = pack8(qaf[s][0], qaf[s][1]);
            *(short8*)(&As[p * 128 * BK + (wave * 32 + 16 + srow) * BK + scol]) = pack8(qaf[s][2], qaf[s][3]);
        } else {
            *(short8*)(&As[p * 128 * BK + (wave * 32 + srow) * BK + scol]) = qa0[s];
            *(short8*)(&As[p * 128 * BK + (wave * 32 + 16 + srow) * BK + scol]) = qa1[s];
        }
        *(short8*)(&Bs[p * 64 * BK + (wave * 16 + srow) * BK + scol]) = pack8(qb0[s], qb1[s]);
    };

#pragma unroll
    for (int j = 0; j < QD; ++j)
        if (j < ITERS) ld(j);
    wrstage(0);

#pragma unroll
    for (int k = 0; k < ITERS; ++k) {
        BARRIER_NODRAIN();
        if (k + QD < ITERS) ld(k + QD);
        if (k + 1 < ITERS) wrstage(k + 1);
        const short* Ap = (const short*)(As + (k & 1) * 128 * BK);
        const short* Bp = (const short*)(Bs + (k & 1) * 64 * BK);
        short8 af[4], bfr[2];
#pragma unroll
        for (int i = 0; i < 4; ++i)
            af[i] = *(const short8*)(Ap + (wr * 64 + i * 16 + r) * BK + q * 8);
#pragma unroll
        for (int j = 0; j < 2; ++j)
            bfr[j] = *(const short8*)(Bp + (wc * 32 + j * 16 + r) * BK + q * 8);
#pragma unroll
        for (int i = 0; i < 4; ++i)
#pragma unroll
            for (int j = 0; j < 2; ++j)
                acc[i][j] = __builtin_amdgcn_mfma_f32_16x16x32_bf16(af[i], bfr[j], acc[i][j], 0, 0, 0);
    }

#pragma unroll
    for (int i = 0; i < 4; ++i) {
        int mrow = m0 + wr * 64 + i * 16 + q * 4;
#pragma unroll
        for (int j = 0; j < 2; ++j) {
            int ncol = n0 + wc * 32 + j * 16 + r;
            if (ncol < Nvalid) {
#pragma unroll
                for (int rr = 0; rr < 4; ++rr) {
                    float v = acc[i][j][rr];
                    if (EPI == 1) {
                        v += bias[ncol];
                        v = v > 20.f ? v : log1pf(__expf(v));
                    }
                    st_dev_f(&C[(long)(mrow + rr) * ldc + ncol], v);
                }
            }
        }
    }
}

struct MegaParams {
    const float *x, *norm_w, *in_w, *conv_w, *conv_b, *xproj_w, *dt_w, *dt_b, *A_log, *D_skip, *out_w;
    float* outp;
    // rotated per layer (normal cached reads, sc1 writes):
    __hip_bfloat16 *xnb;   // [4][L][D]
    float *xz;             // [4][L][4096]
    __hip_bfloat16 *u;     // [4][L][DI]
    __hip_bfloat16 *xdbl;  // [4][L][DTR]
    float *BC;             // [4][L][32]
    float *delta;          // [4][L][DI]
    float *yg;             // [4][L][DI]  (f32)
    float *res;            // [3][L][D]
    // static (sc1 writes AND sc1 reads):
    float *part;           // [KSPLIT][L][XD]
    float *part2;          // [OSPLIT][L][D]
    float *Ach, *Bch;      // [NC][DI][NSTATE]
    uint32_t* bar;
};

// ================= whole network, one dispatch, flush-free barriers =================
__global__ __launch_bounds__(NTHR, 2) void mega_kernel(MegaParams p) {
    const int bid = blockIdx.x;
    const int tid = threadIdx.x;
    __shared__ __align__(16) uint8_t smem[SMEM_BYTES];
    uint32_t bc = 0;

    // ---- pre: RMSNorm layer 0 -> xnb[0] (2 rows per block) ----
    {
        float* red = (float*)smem;
        for (int rr = 0; rr < 2; ++rr) {
            int row = bid * 2 + rr;
            int c0 = tid * 4;
            floatx4 xv = *(const floatx4*)(p.x + (size_t)row * D + c0);
            float s = xv[0] * xv[0] + xv[1] * xv[1] + xv[2] * xv[2] + xv[3] * xv[3];
#pragma unroll
            for (int off = 32; off > 0; off >>= 1) s += __shfl_xor(s, off, 64);
            if ((tid & 63) == 0) red[tid >> 6] = s;
            __syncthreads();
            float inv = rsqrtf((red[0] + red[1] + red[2] + red[3]) * (1.f / D) + 1e-5f);
            uint32_t* dst = (uint32_t*)(p.xnb + (size_t)row * D + c0);
            float a0 = xv[0] * inv * p.norm_w[c0 + 0];
            float a1 = xv[1] * inv * p.norm_w[c0 + 1];
            float a2 = xv[2] * inv * p.norm_w[c0 + 2];
            float a3 = xv[3] * inv * p.norm_w[c0 + 3];
            st_dev_u32(dst + 0, (uint32_t)f2bf(a0) | ((uint32_t)f2bf(a1) << 16));
            st_dev_u32(dst + 1, (uint32_t)f2bf(a2) | ((uint32_t)f2bf(a3) << 16));
            __syncthreads();
        }
    }
    gridbar(p.bar, ++bc);

    for (int l = 0; l < NLAYER; ++l) {
        const __hip_bfloat16* xn_l = p.xnb + (size_t)l * L * D;
        float* xz_l = p.xz + (size_t)l * L * 4096;
        __hip_bfloat16* u_l = p.u + (size_t)l * L * DI;
        __hip_bfloat16* xdbl_l = p.xdbl + (size_t)l * L * DTR;
        float* BC_l = p.BC + (size_t)l * L * 32;
        float* delta_l = p.delta + (size_t)l * L * DI;
        float* yg_l = p.yg + (size_t)l * L * DI;
        const float* inw_l = p.in_w + (size_t)l * 4096 * 1024;
        const float* xpw_l = p.xproj_w + (size_t)l * 96 * 2048;
        const float* dtw_l = p.dt_w + (size_t)l * 2048 * 64;
        const float* dtb_l = p.dt_b + (size_t)l * DI;
        const float* alog_l = p.A_log + (size_t)l * DI * NSTATE;
        const float* outw_l = p.out_w + (size_t)l * 1024 * 2048;

        // ---- S1: in_proj -> xz (512 tiles 128x64, K=1024) ----
        {
            int lid = xmap(bid, 512);
            int bn = lid >> 3, bm = lid & 7;
            gemm_stage<0, 32, false, 4>(smem, xn_l, D, inw_l, D, 4096,
                                        xz_l, 4096, 4096, nullptr, bm, bn, 0);
        }
        gridbar(p.bar, ++bc);

        // ---- S2: causal depthwise conv + SiLU -> u (bf16, paired-d for 4B stores) ----
        {
            const float* __restrict__ cw = p.conv_w + (size_t)l * DI * KCONV;
            const float* __restrict__ cb = p.conv_b + (size_t)l * DI;
#pragma unroll
            for (int it = 0; it < (L * DI / 2) / (GRID * NTHR); ++it) {
                int ip = it * (GRID * NTHR) + bid * NTHR + tid;   // pair index
                int d = (ip * 2) & (DI - 1);
                int t = (ip * 2) >> 11;
                float a0 = cb[d], a1 = cb[d + 1];
#pragma unroll
                for (int k = 0; k < KCONV; ++k) {
                    int tk = t - (KCONV - 1) + k;
                    if (tk >= 0) {
                        a0 += xz_l[(size_t)tk * 4096 + d] * cw[d * KCONV + k];
                        a1 += xz_l[(size_t)tk * 4096 + d + 1] * cw[(d + 1) * KCONV + k];
                    }
                }
                st_dev_u32((uint32_t*)(u_l + (size_t)t * DI + d),
                           (uint32_t)f2bf(siluf(a0)) | ((uint32_t)f2bf(siluf(a1)) << 16));
            }
        }
        gridbar(p.bar, ++bc);

        // ---- S3: x_proj split-K=16 -> part (256 tiles, 4 iters) ----
        if (bid < 256) {
            int lid = xmap(bid, 256);
            int bm = lid & 7, bn = (lid >> 3) & 1, bz = lid >> 4;
            gemm_stage<0, 2048 / (KSPLIT * BK), false, 4>(
                smem, u_l, DI, xpw_l, DI, 96,
                p.part + (size_t)bz * L * XD, XD, XD, nullptr, bm, bn, bz * (2048 / KSPLIT));
        }
        gridbar(p.bar, ++bc);

        // ---- S4: xred (sc1 partial reads) -> xdbl bf16 + BC f32 (paired cols) ----
        {
            int ip = bid * NTHR + tid;   // pair index < L*XD/2 = 49152
            if (ip < (L * XD) / 2) {
                int i2 = ip * 2;
                int t = i2 / XD, col = i2 - t * XD;
                float s0 = 0.f, s1 = 0.f;
#pragma unroll
                for (int sp = 0; sp < KSPLIT; ++sp) {
                    s0 += ld_dev_f(p.part + (size_t)sp * L * XD + i2);
                    s1 += ld_dev_f(p.part + (size_t)sp * L * XD + i2 + 1);
                }
                if (col < DTR) {
                    st_dev_u32((uint32_t*)(xdbl_l + (size_t)t * DTR + col),
                               (uint32_t)f2bf(s0) | ((uint32_t)f2bf(s1) << 16));
                } else {
                    st_dev_f(BC_l + (size_t)t * 32 + (col - DTR), s0);
                    st_dev_f(BC_l + (size_t)t * 32 + (col - DTR) + 1, s1);
                }
            }
        }
        gridbar(p.bar, ++bc);

        // ---- S5: dt_proj -> delta (softplus + bias), 256 tiles ----
        if (bid < 256) {
            int lid = xmap(bid, 256);
            int bn = lid >> 3, bm = lid & 7;
            gemm_stage<1, 2, false, 4>(smem, xdbl_l, DTR, dtw_l, DTR, 2048,
                                       delta_l, DI, DI, dtb_l, bm, bn, 0);
        }
        gridbar(p.bar, ++bc);

        // ---- S6: scanA -> Ach/Bch (sc1 u64 stores), 512 blocks = 8 dgrp x 64 chunks ----
        {
            int d = (bid & 7) * NTHR + tid;
            int c = bid >> 3;
            float* Bsh = (float*)smem;
            Bsh[tid] = BC_l[(size_t)(c * CT + (tid >> 4)) * 32 + (tid & 15)];
            __syncthreads();

            float aval[NSTATE];
            const floatx4* Al4 = (const floatx4*)(alog_l + (size_t)d * NSTATE);
#pragma unroll
            for (int n4 = 0; n4 < 4; ++n4) {
                floatx4 t = Al4[n4];
                aval[n4 * 4 + 0] = -__expf(t[0]);
                aval[n4 * 4 + 1] = -__expf(t[1]);
                aval[n4 * 4 + 2] = -__expf(t[2]);
                aval[n4 * 4 + 3] = -__expf(t[3]);
            }
            float h[NSTATE], ap[NSTATE];
#pragma unroll
            for (int n = 0; n < NSTATE; ++n) { h[n] = 0.f; ap[n] = 1.f; }

            for (int tt = 0; tt < CT; ++tt) {
                int t = c * CT + tt;
                float dl = delta_l[(size_t)t * DI + d];
                float uu = __bfloat162float(u_l[(size_t)t * DI + d]);
                float du = dl * uu;
                const floatx4* Bv = (const floatx4*)(Bsh + tt * NSTATE);
#pragma unroll
                for (int n4 = 0; n4 < 4; ++n4) {
                    floatx4 b = Bv[n4];
#pragma unroll
                    for (int k = 0; k < 4; ++k) {
                        int n = n4 * 4 + k;
                        float a = __expf(dl * aval[n]);
                        h[n] = a * h[n] + du * b[k];
                        ap[n] *= a;
                    }
                }
            }
            float* Ao = p.Ach + ((size_t)c * DI + d) * NSTATE;
            float* Bo = p.Bch + ((size_t)c * DI + d) * NSTATE;
#pragma unroll
            for (int n2 = 0; n2 < 8; ++n2) {
                union { float f[2]; uint64_t u; } ca, cb2;
                ca.f[0] = ap[n2 * 2]; ca.f[1] = ap[n2 * 2 + 1];
                cb2.f[0] = h[n2 * 2]; cb2.f[1] = h[n2 * 2 + 1];
                st_dev_u64(Ao + n2 * 2, ca.u);
                st_dev_u64(Bo + n2 * 2, cb2.u);
            }
        }
        gridbar(p.bar, ++bc);

        // ---- S7: scanB (chunk combine, pipelined sc1 reads; Hinit overwrites Ach) ----
        if (bid < (DI * NSTATE) / NTHR) {
            long i = (long)bid * NTHR + tid;
            const long S = (long)DI * NSTATE;
            constexpr int P = 8;
            float ab[P], bb[P];
#pragma unroll
            for (int j = 0; j < P; ++j) {
                ab[j] = ld_dev_f(p.Ach + (long)j * S + i);
                bb[j] = ld_dev_f(p.Bch + (long)j * S + i);
            }
            float h = 0.f;
#pragma unroll
            for (int c = 0; c < NC; ++c) {
                float a = ab[c & (P - 1)];
                float b = bb[c & (P - 1)];
                st_dev_f(p.Ach + (long)c * S + i, h);  // becomes Hinit
                if (c + P < NC) {
                    ab[c & (P - 1)] = ld_dev_f(p.Ach + (long)(c + P) * S + i);
                    bb[c & (P - 1)] = ld_dev_f(p.Bch + (long)(c + P) * S + i);
                }
                h = a * h + b;
            }
        }
        gridbar(p.bar, ++bc);

        // ---- S8: scanC (replay + gate) -> yg f32 ----
        {
            int d = (bid & 7) * NTHR + tid;
            int c = bid >> 3;
            float* Bsh = (float*)smem;
            float* Csh = Bsh + CT * NSTATE;
            Bsh[tid] = BC_l[(size_t)(c * CT + (tid >> 4)) * 32 + (tid & 15)];
            Csh[tid] = BC_l[(size_t)(c * CT + (tid >> 4)) * 32 + 16 + (tid & 15)];
            __syncthreads();

            float aval[NSTATE];
            const floatx4* Al4 = (const floatx4*)(alog_l + (size_t)d * NSTATE);
#pragma unroll
            for (int n4 = 0; n4 < 4; ++n4) {
                floatx4 t = Al4[n4];
                aval[n4 * 4 + 0] = -__expf(t[0]);
                aval[n4 * 4 + 1] = -__expf(t[1]);
                aval[n4 * 4 + 2] = -__expf(t[2]);
                aval[n4 * 4 + 3] = -__expf(t[3]);
            }
            float h[NSTATE];
#pragma unroll
            for (int n = 0; n < NSTATE; ++n)
                h[n] = ld_dev_f(p.Ach + ((size_t)c * DI + d) * NSTATE + n);
            float dsk = p.D_skip[(size_t)l * DI + d];

            for (int tt = 0; tt < CT; ++tt) {
                int t = c * CT + tt;
                float dl = delta_l[(size_t)t * DI + d];
                float uu = __bfloat162float(u_l[(size_t)t * DI + d]);
                float du = dl * uu;
                const floatx4* Bv = (const floatx4*)(Bsh + tt * NSTATE);
                const floatx4* Cv = (const floatx4*)(Csh + tt * NSTATE);
                float y = 0.f;
#pragma unroll
                for (int n4 = 0; n4 < 4; ++n4) {
                    floatx4 b = Bv[n4];
                    floatx4 cc = Cv[n4];
#pragma unroll
                    for (int k = 0; k < 4; ++k) {
                        int n = n4 * 4 + k;
                        float a = __expf(dl * aval[n]);
                        h[n] = a * h[n] + du * b[k];
                        y += h[n] * cc[k];
                    }
                }
                float z = xz_l[(size_t)t * 4096 + DI + d];
                st_dev_f(yg_l + (size_t)t * DI + d, (y + uu * dsk) * siluf(z));
            }
        }
        gridbar(p.bar, ++bc);

        // ---- S9: out_proj split-K=4 (A = yg f32, converted in staging), 512 tiles ----
        {
            int lid = xmap(bid, 512);
            int bm = lid & 7, bn = (lid >> 3) & 15, bz = lid >> 7;
            gemm_stage<0, 2048 / (OSPLIT * BK), true, 2>(
                smem, yg_l, DI, outw_l, DI, 1024,
                p.part2 + (size_t)bz * L * D, D, 1024, nullptr, bm, bn, bz * (2048 / OSPLIT));
        }
        gridbar(p.bar, ++bc);

        // ---- S10: reduce (sc1 partial reads) + residual -> res/out (+RMSNorm -> next xn) ----
        {
            const float* xin = (l == 0) ? p.x : (p.res + (size_t)(l - 1) * L * D);
            float* resout = (l < NLAYER - 1) ? (p.res + (size_t)l * L * D) : p.outp;
            bool donorm = (l < NLAYER - 1);
            float* red = (float*)smem;
            for (int rr = 0; rr < 2; ++rr) {
                int row = bid * 2 + rr;
                int c0 = tid * 4;
                floatx4 xv = *(const floatx4*)(xin + (size_t)row * D + c0);
                float v[4];
                float ss = 0.f;
#pragma unroll
                for (int j = 0; j < 4; ++j) {
                    float s = xv[j];
#pragma unroll
                    for (int pp = 0; pp < OSPLIT; ++pp)
                        s += ld_dev_f(p.part2 + (size_t)pp * L * D + (size_t)row * D + c0 + j);
                    v[j] = s;
                    st_dev_f(resout + (size_t)row * D + c0 + j, s);
                    ss += s * s;
                }
                if (donorm) {
#pragma unroll
                    for (int off = 32; off > 0; off >>= 1) ss += __shfl_xor(ss, off, 64);
                    if ((tid & 63) == 0) red[tid >> 6] = ss;
                    __syncthreads();
                    float inv = rsqrtf((red[0] + red[1] + red[2] + red[3]) * (1.f / D) + 1e-5f);
                    const float* nw = p.norm_w + (size_t)(l + 1) * D;
                    uint32_t* dst = (uint32_t*)(p.xnb + (size_t)(l + 1) * L * D + (size_t)row * D + c0);
                    float a0 = v[0] * inv * nw[c0 + 0];
                    float a1 = v[1] * inv * nw[c0 + 1];
                    float a2 = v[2] * inv * nw[c0 + 2];
                    float a3 = v[3] * inv * nw[c0 + 3];
                    st_dev_u32(dst + 0, (uint32_t)f2bf(a0) | ((uint32_t)f2bf(a1) << 16));
                    st_dev_u32(dst + 1, (uint32_t)f2bf(a2) | ((uint32_t)f2bf(a3) << 16));
                }
                __syncthreads();
            }
        }
        gridbar(p.bar, ++bc);
    }
}

// ---------------- host orchestration ----------------
extern "C" void kernel_launch(void* const* d_in, const int* in_sizes, int n_in,
                              void* d_out, int out_size, void* d_ws, size_t ws_size,
                              hipStream_t stream) {
    uint8_t* wp = (uint8_t*)d_ws;
    auto alloc = [&](size_t bytes) {
        uint8_t* p = wp;
        wp += (bytes + 255) & ~(size_t)255;
        return p;
    };
    MegaParams prm;
    prm.x      = (const float*)d_in[0];
    prm.norm_w = (const float*)d_in[1];
    prm.in_w   = (const float*)d_in[2];
    prm.conv_w = (const float*)d_in[3];
    prm.conv_b = (const float*)d_in[4];
    prm.xproj_w= (const float*)d_in[5];
    prm.dt_w   = (const float*)d_in[6];
    prm.dt_b   = (const float*)d_in[7];
    prm.A_log  = (const float*)d_in[8];
    prm.D_skip = (const float*)d_in[9];
    prm.out_w  = (const float*)d_in[10];
    prm.outp   = (float*)d_out;

    prm.xnb   = (__hip_bfloat16*)alloc((size_t)4 * L * D * 2);
    prm.xz    = (float*)alloc((size_t)4 * L * 4096 * 4);
    prm.u     = (__hip_bfloat16*)alloc((size_t)4 * L * DI * 2);
    prm.xdbl  = (__hip_bfloat16*)alloc((size_t)4 * L * DTR * 2);
    prm.BC    = (float*)alloc((size_t)4 * L * 32 * 4);
    prm.delta = (float*)alloc((size_t)4 * L * DI * 4);
    prm.yg    = (float*)alloc((size_t)4 * L * DI * 4);
    prm.res   = (float*)alloc((size_t)3 * L * D * 4);
    prm.part  = (float*)alloc((size_t)KSPLIT * L * XD * 4);
    prm.part2 = (float*)alloc((size_t)OSPLIT * L * D * 4);
    prm.Ach   = (float*)alloc((size_t)NC * DI * NSTATE * 4);
    prm.Bch   = (float*)alloc((size_t)NC * DI * NSTATE * 4);
    prm.bar   = (uint32_t*)alloc(4096);

    // barrier counters must start at 0 each launch
    hipMemsetAsync((void*)prm.bar, 0, 4096, stream);

    void* args[] = { &prm };
    hipError_t e = hipLaunchCooperativeKernel((const void*)mega_kernel,
                                              dim3(GRID), dim3(NTHR), args, 0u, stream);
    if (e != hipSuccess) {
        // plain launch: residency guaranteed by __launch_bounds__(256,2) + 24KB LDS
        // -> 2 blocks/CU x 256 CUs = 512 = grid
        hipLaunchKernelGGL(mega_kernel, dim3(GRID), dim3(NTHR), 0, stream, prm);
    }
}

// Round 5
// 618.377 us; speedup vs baseline: 6.1785x; 2.2141x over previous
//
#include <hip/hip_runtime.h>
#include <hip/hip_bf16.h>
#include <stdint.h>

#define L 1024
#define D 1024
#define NLAYER 4
#define NSTATE 16
#define DI 2048
#define DTR 64
#define KCONV 4
#define XD 96      // DTR + 2*NSTATE
#define NC 64      // scan chunks
#define CT 16      // timesteps per chunk (L/NC)
#define KSPLIT 16  // x_proj split-K (atomic epilogue)
#define OSPLIT 4   // out_proj split-K (atomic epilogue)
#define BK 32
#define DIST 4     // GEMM prefetch depth (iterations)

typedef __attribute__((ext_vector_type(8))) short short8;
typedef __attribute__((ext_vector_type(4))) float floatx4;

__device__ __forceinline__ float siluf(float x) { return x / (1.f + __expf(-x)); }

__device__ __forceinline__ unsigned short f2bf(float x) {
    __hip_bfloat16 b = __float2bfloat16(x);
    return *reinterpret_cast<unsigned short*>(&b);
}

__device__ __forceinline__ short8 pack8(floatx4 a, floatx4 b) {
    short8 o;
    o[0] = (short)f2bf(a.x); o[1] = (short)f2bf(a.y);
    o[2] = (short)f2bf(a.z); o[3] = (short)f2bf(a.w);
    o[4] = (short)f2bf(b.x); o[5] = (short)f2bf(b.y);
    o[6] = (short)f2bf(b.z); o[7] = (short)f2bf(b.w);
    return o;
}

// Barrier that does NOT drain vmcnt: deep global-load prefetches stay in flight.
#define BARRIER_NODRAIN() asm volatile("s_waitcnt lgkmcnt(0)\n\ts_barrier" ::: "memory")

// ---------------- RMSNorm -> bf16; optionally also copy src -> out (residual seed) ----------------
template <bool COPYOUT>
__global__ __launch_bounds__(256) void rmsnorm_kernel(const float* __restrict__ x,
                                                      const float* __restrict__ w,
                                                      __hip_bfloat16* __restrict__ xn,
                                                      float* __restrict__ outcpy) {
    int row = blockIdx.x;
    const float* xr = x + (size_t)row * D;
    float v[4];
    float s = 0.f;
#pragma unroll
    for (int i = 0; i < 4; ++i) {
        v[i] = xr[threadIdx.x + i * 256];
        s += v[i] * v[i];
    }
#pragma unroll
    for (int off = 32; off > 0; off >>= 1) s += __shfl_xor(s, off, 64);
    __shared__ float red[4];
    int wave = threadIdx.x >> 6;
    if ((threadIdx.x & 63) == 0) red[wave] = s;
    __syncthreads();
    float tot = red[0] + red[1] + red[2] + red[3];
    float inv = rsqrtf(tot * (1.f / D) + 1e-5f);
#pragma unroll
    for (int i = 0; i < 4; ++i) {
        int c = threadIdx.x + i * 256;
        xn[(size_t)row * D + c] = __float2bfloat16(v[i] * inv * w[c]);
        if (COPYOUT) outcpy[(size_t)row * D + c] = v[i];
    }
}

// ---------------- pipelined GEMM (128x64 tile): C[M,N] = A[M,K] * B[N,K]^T ----------------
// A bf16 (AF32=false) or f32 converted during staging (AF32=true); B fp32 -> bf16.
// EPI: 0 plain store; 1 softplus(c + bias[n]) store; 2 atomicAdd (split-K accumulate).
template <int EPI, int ITERS, bool AF32, int QD>
__global__ __launch_bounds__(256, 2) void gemm_pipe(
    const void* __restrict__ Aptr, int lda,
    const float* __restrict__ Bw, int ldb, int Brows,
    float* __restrict__ C, int ldc, int Nvalid,
    const float* __restrict__ bias) {
    __shared__ __align__(16) __hip_bfloat16 As[2][128 * BK];
    __shared__ __align__(16) __hip_bfloat16 Bs[2][64 * BK];
    int tid = threadIdx.x;
    int wave = tid >> 6, lane = tid & 63;

    int gxy = gridDim.x * gridDim.y;
    int total = gxy * gridDim.z;
    int flat = (blockIdx.z * gridDim.y + blockIdx.y) * gridDim.x + blockIdx.x;
    int bm, bn, bz;
    if ((total & 7) == 0) {
        int lid = (flat & 7) * (total >> 3) + (flat >> 3);
        bz = lid / gxy;
        int rem = lid - bz * gxy;
        bn = rem / gridDim.y;
        bm = rem - bn * gridDim.y;
    } else {
        bm = blockIdx.y; bn = blockIdx.x; bz = blockIdx.z;
    }

    int m0 = bm * 128, n0 = bn * 64;
    int k_base = bz * (ITERS * BK);
    int wr = wave >> 1, wc = wave & 1;
    int srow = lane >> 2, scol = (lane & 3) * 8;
    int q = lane >> 4, r = lane & 15;

    floatx4 acc[4][2] = {};

    int arow0 = m0 + wave * 32 + srow;
    const __hip_bfloat16* gA0 = nullptr; const __hip_bfloat16* gA1 = nullptr;
    const float* gAf0 = nullptr; const float* gAf1 = nullptr;
    if (AF32) {
        gAf0 = (const float*)Aptr + (long)arow0 * lda + scol + k_base;
        gAf1 = gAf0 + (long)16 * lda;
    } else {
        gA0 = (const __hip_bfloat16*)Aptr + (long)arow0 * lda + scol + k_base;
        gA1 = gA0 + (long)16 * lda;
    }
    int bnrow = n0 + wave * 16 + srow;
    const float* gB = Bw + (long)bnrow * ldb + scol + k_base;
    bool bok = bnrow < Brows;

    short8 qa0[QD], qa1[QD];
    floatx4 qaf[AF32 ? QD : 1][4];
    floatx4 qb0[QD] = {}, qb1[QD] = {};

    auto ld = [&](int j) {
        int k0 = j * BK;
        int s = j & (QD - 1);
        if (AF32) {
            qaf[s][0] = *(const floatx4*)(gAf0 + k0);
            qaf[s][1] = *(const floatx4*)(gAf0 + k0 + 4);
            qaf[s][2] = *(const floatx4*)(gAf1 + k0);
            qaf[s][3] = *(const floatx4*)(gAf1 + k0 + 4);
        } else {
            qa0[s] = *(const short8*)(gA0 + k0);
            qa1[s] = *(const short8*)(gA1 + k0);
        }
        if (bok) {
            qb0[s] = *(const floatx4*)(gB + k0);
            qb1[s] = *(const floatx4*)(gB + k0 + 4);
        }
    };
    auto wrstage = [&](int j) {
        int p = j & 1, s = j & (QD - 1);
        if (AF32) {
            *(short8*)(&As[p][(wave * 32 + srow) * BK + scol]) = pack8(qaf[s][0], qaf[s][1]);
            *(short8*)(&As[p][(wave * 32 + 16 + srow) * BK + scol]) = pack8(qaf[s][2], qaf[s][3]);
        } else {
            *(short8*)(&As[p][(wave * 32 + srow) * BK + scol]) = qa0[s];
            *(short8*)(&As[p][(wave * 32 + 16 + srow) * BK + scol]) = qa1[s];
        }
        *(short8*)(&Bs[p][(wave * 16 + srow) * BK + scol]) = pack8(qb0[s], qb1[s]);
    };

#pragma unroll
    for (int j = 0; j < QD; ++j)
        if (j < ITERS) ld(j);
    wrstage(0);

#pragma unroll
    for (int k = 0; k < ITERS; ++k) {
        BARRIER_NODRAIN();
        if (k + QD < ITERS) ld(k + QD);
        if (k + 1 < ITERS) wrstage(k + 1);
        const short* Ap = (const short*)As[k & 1];
        const short* Bp = (const short*)Bs[k & 1];
        short8 af[4], bfr[2];
#pragma unroll
        for (int i = 0; i < 4; ++i)
            af[i] = *(const short8*)(Ap + (wr * 64 + i * 16 + r) * BK + q * 8);
#pragma unroll
        for (int j = 0; j < 2; ++j)
            bfr[j] = *(const short8*)(Bp + (wc * 32 + j * 16 + r) * BK + q * 8);
#pragma unroll
        for (int i = 0; i < 4; ++i)
#pragma unroll
            for (int j = 0; j < 2; ++j)
                acc[i][j] = __builtin_amdgcn_mfma_f32_16x16x32_bf16(af[i], bfr[j], acc[i][j], 0, 0, 0);
    }

#pragma unroll
    for (int i = 0; i < 4; ++i) {
        int mrow = m0 + wr * 64 + i * 16 + q * 4;
#pragma unroll
        for (int j = 0; j < 2; ++j) {
            int ncol = n0 + wc * 32 + j * 16 + r;
            if (ncol < Nvalid) {
#pragma unroll
                for (int rr = 0; rr < 4; ++rr) {
                    float v = acc[i][j][rr];
                    int m = mrow + rr;
                    if (EPI == 1) {
                        v += bias[ncol];
                        v = v > 20.f ? v : log1pf(__expf(v));
                    }
                    if (EPI == 2) atomicAdd(&C[(long)m * ldc + ncol], v);
                    else C[(long)m * ldc + ncol] = v;
                }
            }
        }
    }
}

// ---------------- 128x128-tile GEMM, per-wave 64x64 (2x MFMA:ds_read ratio) ----------------
// EPI: 0 plain store; 2 atomicAdd (split-K accumulate into residual buffer).
template <int ITERS, int EPI>
__global__ __launch_bounds__(256, 1) void gemm128(
    const __hip_bfloat16* __restrict__ A, int lda,
    const float* __restrict__ Bw, int ldb, int Brows,
    float* __restrict__ C, int ldc) {
    __shared__ __align__(16) __hip_bfloat16 As[2][128 * BK];
    __shared__ __align__(16) __hip_bfloat16 Bs[2][128 * BK];
    int tid = threadIdx.x;
    int wave = tid >> 6, lane = tid & 63;

    int gxy = gridDim.x * gridDim.y;
    int total = gxy * gridDim.z;
    int flat = (blockIdx.z * gridDim.y + blockIdx.y) * gridDim.x + blockIdx.x;
    int bm, bn, bz;
    if ((total & 7) == 0) {
        int lid = (flat & 7) * (total >> 3) + (flat >> 3);
        bz = lid / gxy;
        int rem = lid - bz * gxy;
        bn = rem / gridDim.y;
        bm = rem - bn * gridDim.y;
    } else {
        bm = blockIdx.y; bn = blockIdx.x; bz = blockIdx.z;
    }

    int m0 = bm * 128, n0 = bn * 128;
    int k_base = bz * (ITERS * BK);
    int wr = wave >> 1, wc = wave & 1;
    int srow = lane >> 2, scol = (lane & 3) * 8;
    int q = lane >> 4, r = lane & 15;

    floatx4 acc[4][4] = {};

    const __hip_bfloat16* gA0 = A + (long)(m0 + wave * 32 + srow) * lda + scol + k_base;
    const __hip_bfloat16* gA1 = gA0 + (long)16 * lda;
    int bn0 = n0 + wave * 32 + srow;
    const float* gB0 = Bw + (long)bn0 * ldb + scol + k_base;
    const float* gB1 = gB0 + (long)16 * ldb;
    bool bok0 = bn0 < Brows, bok1 = (bn0 + 16) < Brows;

    short8 qa0[DIST], qa1[DIST];
    floatx4 qb0[DIST] = {}, qb1[DIST] = {}, qb2[DIST] = {}, qb3[DIST] = {};

    auto ld = [&](int j) {
        int k0 = j * BK;
        int s = j & (DIST - 1);
        qa0[s] = *(const short8*)(gA0 + k0);
        qa1[s] = *(const short8*)(gA1 + k0);
        if (bok0) {
            qb0[s] = *(const floatx4*)(gB0 + k0);
            qb1[s] = *(const floatx4*)(gB0 + k0 + 4);
        }
        if (bok1) {
            qb2[s] = *(const floatx4*)(gB1 + k0);
            qb3[s] = *(const floatx4*)(gB1 + k0 + 4);
        }
    };
    auto wrstage = [&](int j) {
        int p = j & 1, s = j & (DIST - 1);
        *(short8*)(&As[p][(wave * 32 + srow) * BK + scol]) = qa0[s];
        *(short8*)(&As[p][(wave * 32 + 16 + srow) * BK + scol]) = qa1[s];
        *(short8*)(&Bs[p][(wave * 32 + srow) * BK + scol]) = pack8(qb0[s], qb1[s]);
        *(short8*)(&Bs[p][(wave * 32 + 16 + srow) * BK + scol]) = pack8(qb2[s], qb3[s]);
    };

#pragma unroll
    for (int j = 0; j < DIST; ++j)
        if (j < ITERS) ld(j);
    wrstage(0);

#pragma unroll
    for (int k = 0; k < ITERS; ++k) {
        BARRIER_NODRAIN();
        if (k + DIST < ITERS) ld(k + DIST);
        if (k + 1 < ITERS) wrstage(k + 1);
        const short* Ap = (const short*)As[k & 1];
        const short* Bp = (const short*)Bs[k & 1];
        short8 af[4], bfr[4];
#pragma unroll
        for (int i = 0; i < 4; ++i)
            af[i] = *(const short8*)(Ap + (wr * 64 + i * 16 + r) * BK + q * 8);
#pragma unroll
        for (int j = 0; j < 4; ++j)
            bfr[j] = *(const short8*)(Bp + (wc * 64 + j * 16 + r) * BK + q * 8);
#pragma unroll
        for (int i = 0; i < 4; ++i)
#pragma unroll
            for (int j = 0; j < 4; ++j)
                acc[i][j] = __builtin_amdgcn_mfma_f32_16x16x32_bf16(af[i], bfr[j], acc[i][j], 0, 0, 0);
    }

#pragma unroll
    for (int i = 0; i < 4; ++i) {
        int mrow = m0 + wr * 64 + i * 16 + q * 4;
#pragma unroll
        for (int j = 0; j < 4; ++j) {
            int ncol = n0 + wc * 64 + j * 16 + r;
#pragma unroll
            for (int rr = 0; rr < 4; ++rr) {
                if (EPI == 2) atomicAdd(&C[(long)(mrow + rr) * ldc + ncol], acc[i][j][rr]);
                else C[(long)(mrow + rr) * ldc + ncol] = acc[i][j][rr];
            }
        }
    }
}

// ---------------- causal depthwise conv + bias + SiLU -> bf16; spare blocks zero xdbl96 ----------------
__global__ __launch_bounds__(256) void conv_silu_kernel(const float* __restrict__ xz,
                                                        const float* __restrict__ cw,
                                                        const float* __restrict__ cb,
                                                        __hip_bfloat16* __restrict__ u,
                                                        float* __restrict__ xdbl96) {
    int idx = blockIdx.x * 256 + threadIdx.x;  // t*DI + d
    if (blockIdx.x < (L * XD) / 256) xdbl96[idx] = 0.f;  // zero the x_proj accumulator
    int d = idx & (DI - 1);
    int t = idx >> 11;
    float acc = cb[d];
#pragma unroll
    for (int k = 0; k < KCONV; ++k) {
        int tk = t - (KCONV - 1) + k;
        if (tk >= 0) acc += xz[(size_t)tk * (2 * DI) + d] * cw[d * KCONV + k];
    }
    u[idx] = __float2bfloat16(siluf(acc));
}

// ---------------- selective scan: phase A (per-chunk aggregates) ----------------
__global__ __launch_bounds__(256) void scanA_kernel(const float* __restrict__ delta,
                                                    const __hip_bfloat16* __restrict__ u,
                                                    const float* __restrict__ xdbl96,
                                                    const float* __restrict__ Alog,
                                                    float* __restrict__ Ach,
                                                    float* __restrict__ Bch) {
    int d = blockIdx.x * 256 + threadIdx.x;
    int c = blockIdx.y;
    __shared__ __align__(16) float Bsh[CT * NSTATE];
    int tt0 = threadIdx.x >> 4, c0 = threadIdx.x & 15;
    Bsh[threadIdx.x] = xdbl96[(size_t)(c * CT + tt0) * XD + DTR + c0];
    __syncthreads();

    float aval[NSTATE];
    const float4* Al4 = (const float4*)(Alog + (size_t)d * NSTATE);
#pragma unroll
    for (int n4 = 0; n4 < 4; ++n4) {
        float4 t = Al4[n4];
        aval[n4 * 4 + 0] = -__expf(t.x);
        aval[n4 * 4 + 1] = -__expf(t.y);
        aval[n4 * 4 + 2] = -__expf(t.z);
        aval[n4 * 4 + 3] = -__expf(t.w);
    }
    float h[NSTATE], ap[NSTATE];
#pragma unroll
    for (int n = 0; n < NSTATE; ++n) { h[n] = 0.f; ap[n] = 1.f; }

    for (int tt = 0; tt < CT; ++tt) {
        int t = c * CT + tt;
        float dl = delta[(size_t)t * DI + d];
        float uu = __bfloat162float(u[(size_t)t * DI + d]);
        float du = dl * uu;
        const float4* Bv = (const float4*)(Bsh + tt * NSTATE);
#pragma unroll
        for (int n4 = 0; n4 < 4; ++n4) {
            float4 b = Bv[n4];
            float bb[4] = {b.x, b.y, b.z, b.w};
#pragma unroll
            for (int k = 0; k < 4; ++k) {
                int n = n4 * 4 + k;
                float a = __expf(dl * aval[n]);
                h[n] = a * h[n] + du * bb[k];
                ap[n] *= a;
            }
        }
    }
    float4* Ao = (float4*)(Ach + ((size_t)c * DI + d) * NSTATE);
    float4* Bo = (float4*)(Bch + ((size_t)c * DI + d) * NSTATE);
#pragma unroll
    for (int n4 = 0; n4 < 4; ++n4) {
        Ao[n4] = make_float4(ap[n4 * 4], ap[n4 * 4 + 1], ap[n4 * 4 + 2], ap[n4 * 4 + 3]);
        Bo[n4] = make_float4(h[n4 * 4], h[n4 * 4 + 1], h[n4 * 4 + 2], h[n4 * 4 + 3]);
    }
}

// ---------------- scan phase B: sequential chunk combine, software-pipelined loads ----------------
__global__ __launch_bounds__(256) void scanB_kernel(float* __restrict__ Ach,
                                                    const float* __restrict__ Bch) {
    long i = blockIdx.x * 256 + threadIdx.x;  // < DI*NSTATE
    const long S = (long)DI * NSTATE;
    constexpr int P = 8;
    float ab[P], bb[P];
#pragma unroll
    for (int j = 0; j < P; ++j) {
        ab[j] = Ach[(long)j * S + i];
        bb[j] = Bch[(long)j * S + i];
    }
    float h = 0.f;
#pragma unroll
    for (int c = 0; c < NC; ++c) {
        float a = ab[c & (P - 1)];
        float b = bb[c & (P - 1)];
        Ach[(long)c * S + i] = h;  // becomes Hinit
        if (c + P < NC) {
            ab[c & (P - 1)] = Ach[(long)(c + P) * S + i];
            bb[c & (P - 1)] = Bch[(long)(c + P) * S + i];
        }
        h = a * h + b;
    }
}

// ---------------- scan phase C: replay with init state, fused gate -> yg bf16 ----------------
__global__ __launch_bounds__(256) void scanC_kernel(const float* __restrict__ delta,
                                                    const __hip_bfloat16* __restrict__ u,
                                                    const float* __restrict__ xdbl96,
                                                    const float* __restrict__ Alog,
                                                    const float* __restrict__ Hin,
                                                    const float* __restrict__ xz,
                                                    const float* __restrict__ Dskip,
                                                    __hip_bfloat16* __restrict__ yg) {
    int d = blockIdx.x * 256 + threadIdx.x;
    int c = blockIdx.y;
    __shared__ __align__(16) float Bsh[CT * NSTATE];
    __shared__ __align__(16) float Csh[CT * NSTATE];
    int tt0 = threadIdx.x >> 4, c0 = threadIdx.x & 15;
    Bsh[threadIdx.x] = xdbl96[(size_t)(c * CT + tt0) * XD + DTR + c0];
    Csh[threadIdx.x] = xdbl96[(size_t)(c * CT + tt0) * XD + DTR + 16 + c0];
    __syncthreads();

    float aval[NSTATE];
    const float4* Al4 = (const float4*)(Alog + (size_t)d * NSTATE);
#pragma unroll
    for (int n4 = 0; n4 < 4; ++n4) {
        float4 t = Al4[n4];
        aval[n4 * 4 + 0] = -__expf(t.x);
        aval[n4 * 4 + 1] = -__expf(t.y);
        aval[n4 * 4 + 2] = -__expf(t.z);
        aval[n4 * 4 + 3] = -__expf(t.w);
    }
    float h[NSTATE];
    const float4* Hi = (const float4*)(Hin + ((size_t)c * DI + d) * NSTATE);
#pragma unroll
    for (int n4 = 0; n4 < 4; ++n4) {
        float4 t = Hi[n4];
        h[n4 * 4 + 0] = t.x; h[n4 * 4 + 1] = t.y; h[n4 * 4 + 2] = t.z; h[n4 * 4 + 3] = t.w;
    }
    float dsk = Dskip[d];

    for (int tt = 0; tt < CT; ++tt) {
        int t = c * CT + tt;
        float dl = delta[(size_t)t * DI + d];
        float uu = __bfloat162float(u[(size_t)t * DI + d]);
        float du = dl * uu;
        const float4* Bv = (const float4*)(Bsh + tt * NSTATE);
        const float4* Cv = (const float4*)(Csh + tt * NSTATE);
        float y = 0.f;
#pragma unroll
        for (int n4 = 0; n4 < 4; ++n4) {
            float4 b = Bv[n4];
            float4 cc = Cv[n4];
            float bb[4] = {b.x, b.y, b.z, b.w};
            float cv[4] = {cc.x, cc.y, cc.z, cc.w};
#pragma unroll
            for (int k = 0; k < 4; ++k) {
                int n = n4 * 4 + k;
                float a = __expf(dl * aval[n]);
                h[n] = a * h[n] + du * bb[k];
                y += h[n] * cv[k];
            }
        }
        float z = xz[(size_t)t * (2 * DI) + DI + d];
        yg[(size_t)t * DI + d] = __float2bfloat16((y + uu * dsk) * siluf(z));
    }
}

// ---------------- host orchestration ----------------
// Residual-by-accumulation: out starts as x (seeded by rmsnorm0); each layer's
// out_proj atomicAdds its projection into out -> out is always the running residual.
extern "C" void kernel_launch(void* const* d_in, const int* in_sizes, int n_in,
                              void* d_out, int out_size, void* d_ws, size_t ws_size,
                              hipStream_t stream) {
    const float* x      = (const float*)d_in[0];
    const float* norm_w = (const float*)d_in[1];
    const float* in_w   = (const float*)d_in[2];
    const float* conv_w = (const float*)d_in[3];
    const float* conv_b = (const float*)d_in[4];
    const float* xproj_w= (const float*)d_in[5];
    const float* dt_w   = (const float*)d_in[6];
    const float* dt_b   = (const float*)d_in[7];
    const float* A_log  = (const float*)d_in[8];
    const float* D_skip = (const float*)d_in[9];
    const float* out_w  = (const float*)d_in[10];
    float* out = (float*)d_out;

    uint8_t* wp = (uint8_t*)d_ws;
    auto alloc = [&](size_t bytes) {
        uint8_t* p = wp;
        wp += (bytes + 255) & ~(size_t)255;
        return p;
    };
    __hip_bfloat16* xn_bf   = (__hip_bfloat16*)alloc((size_t)L * D * 2);
    float*          xz      = (float*)alloc((size_t)L * 2 * DI * 4);
    __hip_bfloat16* u_bf    = (__hip_bfloat16*)alloc((size_t)L * DI * 2);
    float*          xdbl96  = (float*)alloc((size_t)L * XD * 4);
    float*          delta   = (float*)alloc((size_t)L * DI * 4);
    __hip_bfloat16* yg_bf   = (__hip_bfloat16*)alloc((size_t)L * DI * 2);
    float*          Ach     = (float*)alloc((size_t)NC * DI * NSTATE * 4);  // Hinit aliases this
    float*          Bch     = (float*)alloc((size_t)NC * DI * NSTATE * 4);

    // seed: xn = rms(x)*w0, out = x  (out accumulates every layer's out_proj)
    rmsnorm_kernel<true><<<L, 256, 0, stream>>>(x, norm_w, xn_bf, out);

    for (int l = 0; l < NLAYER; ++l) {
        // in_proj: [1024,1024] x [4096,1024]^T -> xz  (128x128 tiles, 256 blocks, 32 iters)
        gemm128<32, 0><<<dim3(4096 / 128, L / 128, 1), 256, 0, stream>>>(
            xn_bf, D, in_w + (size_t)l * 4096 * 1024, D, 4096, xz, 4096);

        // conv+SiLU -> u; spare capacity zeroes xdbl96 for the atomic split-K below
        conv_silu_kernel<<<L * DI / 256, 256, 0, stream>>>(
            xz, conv_w + (size_t)l * DI * KCONV, conv_b + (size_t)l * DI, u_bf, xdbl96);

        // x_proj split-K=16, atomicAdd epilogue -> xdbl96[L][96]  (256 tiles, 4 iters)
        gemm_pipe<2, 2048 / (KSPLIT * BK), false, 4><<<dim3(2, L / 128, KSPLIT), 256, 0, stream>>>(
            u_bf, DI, xproj_w + (size_t)l * 96 * 2048, DI, 96,
            xdbl96, XD, XD, nullptr);

        // dt_proj: A = xdbl96 f32 (converted in staging), softplus(+bias) -> delta  (2 iters)
        gemm_pipe<1, 2, true, 2><<<dim3(2048 / 64, L / 128, 1), 256, 0, stream>>>(
            xdbl96, XD, dt_w + (size_t)l * 2048 * 64, DTR, 2048,
            delta, DI, DI, dt_b + (size_t)l * DI);

        scanA_kernel<<<dim3(DI / 256, NC), 256, 0, stream>>>(
            delta, u_bf, xdbl96, A_log + (size_t)l * DI * NSTATE, Ach, Bch);
        scanB_kernel<<<(DI * NSTATE) / 256, 256, 0, stream>>>(Ach, Bch);
        scanC_kernel<<<dim3(DI / 256, NC), 256, 0, stream>>>(
            delta, u_bf, xdbl96, A_log + (size_t)l * DI * NSTATE, Ach, xz,
            D_skip + (size_t)l * DI, yg_bf);

        // out_proj split-K=4, atomicAdd into out (residual accumulates in place)
        gemm128<2048 / (OSPLIT * BK), 2><<<dim3(1024 / 128, L / 128, OSPLIT), 256, 0, stream>>>(
            yg_bf, DI, out_w + (size_t)l * 1024 * 2048, DI, 1024, out, D);

        // next layer's RMSNorm input (layers 0-2 only)
        if (l < NLAYER - 1)
            rmsnorm_kernel<false><<<L, 256, 0, stream>>>(
                out, norm_w + (size_t)(l + 1) * D, xn_bf, nullptr);
    }
}